// Round 12
// baseline (54.309 us; speedup 1.0000x reference)
//
#include <hip/hip_runtime.h>
#include <stdint.h>

// VQ-VAE quantization: B=131072 rows of z (D=64) vs N_E=1024 codes.
// Outputs (flat f32): z_q [131072*64] | loss [1] | idx [131072] | var(idx,ddof=1) [1]
//
// R12: codes RESIDENT in LDS for the whole kernel + clean 2-kernel split.
//  K1 vq_dist: 512 blocks x 256 thr. Block b: codebook half (b&1) staged ONCE
//     into 66 KB LDS (one vmcnt(0)+barrier total); then a pure loop with NO
//     staging, NO barriers, NO manual waits: 2 iters x 32 tiles x
//     {3 ds_read, 8 MFMA, key-VALU}; z for iter 1 register-prefetched.
//     Writes 2 packed keys/row + ||z||^2 to ws.
//  K2 vq_out: combine 2 keys -> idx; gather z_q; write idx; loss/var partials.
//  K3 vq_final: scalar reduce.
// key = (float_bits(0.5+||e||^2-2z.e) & ~1023) | code ; unsigned min == argmin.

typedef __attribute__((ext_vector_type(8))) __bf16 bf16x8;
typedef __attribute__((ext_vector_type(4))) float f32x4;

#define OUT_LOSS 8388608
#define OUT_IDX  8388609
#define OUT_VAR  8519681

// workspace layout (bytes)
#define WS_LOSS  0            // float[2048] per-block loss partials (vq_out)
#define WS_S1    8192         // int[2048] sum(idx)
#define WS_S2    16384        // int[2048] sum(idx^2)
#define WS_EFRAG 24576        // bf16x8[64 tiles * 2 ksteps * 64 lanes] = 128 KB
#define WS_EE    155648       // float[1024] ||e||^2 + 0.5 (4 KB)
#define WS_KEY   159744       // unsigned[131072][2] packed keys (1 MB)
#define WS_ZZ    1208320      // float[131072] ||z_row||^2 (512 KB)

__device__ __forceinline__ void gld_lds16(const void* g, void* l) {
  __builtin_amdgcn_global_load_lds(
      (const __attribute__((address_space(1))) unsigned*)g,
      (__attribute__((address_space(3))) unsigned*)l, 16, 0, 0);
}

// ---- K0: prep codebook fragments -----------------------------------------
// A-frag for mfma_f32_16x16x32_bf16: lane l holds code row (t*16 + (l&15)),
// k = kstep*32 + (l>>4)*8 + i. Values are -2*e.
__global__ void vq_prep(const float* __restrict__ emb, char* __restrict__ ws) {
  bf16x8* efrag = (bf16x8*)(ws + WS_EFRAG);
  float* eeoff = (float*)(ws + WS_EE);
  const int t = blockIdx.x;    // tile 0..63
  const int l = threadIdx.x;   // 0..63
  const int n = t * 16 + (l & 15);
  const int kb0 = (l >> 4) * 8;
  const float* er = emb + n * 64;
  for (int j = 0; j < 2; ++j) {
    const int kb = j * 32 + kb0;
    bf16x8 h;
#pragma unroll
    for (int i = 0; i < 8; ++i) h[i] = (__bf16)(-2.0f * er[kb + i]);
    efrag[(t * 2 + j) * 64 + l] = h;
  }
  if (l < 16) {
    const float* e2 = emb + (t * 16 + l) * 64;
    float s = 0.f;
#pragma unroll
    for (int d = 0; d < 64; ++d) s += e2[d] * e2[d];
    eeoff[t * 16 + l] = s + 0.5f;
  }
}

// ---- K1: distances + per-half argmin --------------------------------------
// 512 blocks x 256 thr (4 waves). half = b&1 (32 code tiles); row group =
// b>>1 (512 rows). Wave w, iter it -> rows (b>>1)*512 + it*256 + w*64 .. +63.
__global__ void __launch_bounds__(256) vq_dist(
    const float* __restrict__ z, char* __restrict__ ws) {
  __shared__ char sfrag[65536];     // this half's 32 tiles, resident forever
  __shared__ float see[512];        // this half's ||e||^2 + 0.5

  const int tid = threadIdx.x;
  const int wave = tid >> 6, lane = tid & 63;
  const int lr = lane & 15, ksl = lane >> 4;
  const int k0 = ksl * 8;
  const int half = blockIdx.x & 1;
  const int rb0 = (blockIdx.x >> 1) * 512 + wave * 64;   // iter 0 rows

  unsigned* wkey = (unsigned*)(ws + WS_KEY);
  float* wzz = (float*)(ws + WS_ZZ);

  // iter-0 z loads first (plain loads; compiler tracks their deps)
  f32x4 zr[16];
#pragma unroll
  for (int r = 0; r < 4; ++r) {
    const float* zp = z + (size_t)(rb0 + r * 16 + lr) * 64;
    zr[r * 4 + 0] = *(const f32x4*)(zp + k0);
    zr[r * 4 + 1] = *(const f32x4*)(zp + k0 + 4);
    zr[r * 4 + 2] = *(const f32x4*)(zp + 32 + k0);
    zr[r * 4 + 3] = *(const f32x4*)(zp + 32 + k0 + 4);
  }

  // one-shot staging of this half's codebook fragments + ee (66 KB)
#pragma unroll
  for (int i = 0; i < 16; ++i)
    gld_lds16(ws + WS_EFRAG + half * 65536 + i * 4096 + wave * 1024 + lane * 16,
              sfrag + i * 4096 + wave * 1024);
  if (wave < 2)
    gld_lds16(ws + WS_EE + half * 2048 + wave * 1024 + lane * 16,
              (char*)see + wave * 1024);
  asm volatile("s_waitcnt vmcnt(0)" ::: "memory");
  __syncthreads();                  // the ONLY barrier

  const bf16x8* sf = (const bf16x8*)sfrag;
  const unsigned kj0 = (unsigned)(ksl * 4), kj1 = kj0 + 1, kj2 = kj0 + 2, kj3 = kj0 + 3;

#pragma unroll
  for (int it = 0; it < 2; ++it) {
    const int rbase = rb0 + it * 256;
    // convert current z to bf16 B-fragments + ||z||^2 (half 0 publishes zz)
    bf16x8 zf[4][2];
    float zz[4];
#pragma unroll
    for (int r = 0; r < 4; ++r) {
      float s = 0.f;
#pragma unroll
      for (int i = 0; i < 4; ++i) {
        zf[r][0][i] = (__bf16)zr[r * 4 + 0][i]; zf[r][0][4 + i] = (__bf16)zr[r * 4 + 1][i];
        zf[r][1][i] = (__bf16)zr[r * 4 + 2][i]; zf[r][1][4 + i] = (__bf16)zr[r * 4 + 3][i];
        s += zr[r * 4 + 0][i] * zr[r * 4 + 0][i] + zr[r * 4 + 1][i] * zr[r * 4 + 1][i]
           + zr[r * 4 + 2][i] * zr[r * 4 + 2][i] + zr[r * 4 + 3][i] * zr[r * 4 + 3][i];
      }
      s += __shfl_xor(s, 16, 64);
      s += __shfl_xor(s, 32, 64);
      zz[r] = s;
    }
    // register-prefetch next iteration's z across this iteration's compute
    if (it == 0) {
#pragma unroll
      for (int r = 0; r < 4; ++r) {
        const float* zp = z + (size_t)(rb0 + 256 + r * 16 + lr) * 64;
        zr[r * 4 + 0] = *(const f32x4*)(zp + k0);
        zr[r * 4 + 1] = *(const f32x4*)(zp + k0 + 4);
        zr[r * 4 + 2] = *(const f32x4*)(zp + 32 + k0);
        zr[r * 4 + 3] = *(const f32x4*)(zp + 32 + k0 + 4);
      }
    }

    unsigned rk[4];
#pragma unroll
    for (int r = 0; r < 4; ++r) rk[r] = 0xFFFFFFFFu;

#pragma unroll 4
    for (int tt = 0; tt < 32; ++tt) {
      bf16x8 e0 = sf[(tt * 2 + 0) * 64 + lane];   // conflict-free b128
      bf16x8 e1 = sf[(tt * 2 + 1) * 64 + lane];
      const f32x4 ee = *(const f32x4*)(see + tt * 16 + ksl * 4);
      const unsigned g16 = (unsigned)((half * 32 + tt) * 16);
#pragma unroll
      for (int r = 0; r < 4; ++r) {               // 4 independent MFMA chains
        f32x4 a = __builtin_amdgcn_mfma_f32_16x16x32_bf16(e0, zf[r][0], ee, 0, 0, 0);
        a = __builtin_amdgcn_mfma_f32_16x16x32_bf16(e1, zf[r][1], a, 0, 0, 0);
        const unsigned t0 = (__float_as_uint(a[0]) & 0xFFFFFC00u) | kj0;
        const unsigned t1 = (__float_as_uint(a[1]) & 0xFFFFFC00u) | kj1;
        const unsigned t2 = (__float_as_uint(a[2]) & 0xFFFFFC00u) | kj2;
        const unsigned t3 = (__float_as_uint(a[3]) & 0xFFFFFC00u) | kj3;
        rk[r] = min(rk[r], min(min(t0, t1), min(t2, t3)) + g16);
      }
    }

    // reduce across the 4 ksl lane groups; store this half's per-row keys
#pragma unroll
    for (int r = 0; r < 4; ++r) {
      rk[r] = min(rk[r], (unsigned)__shfl_xor((int)rk[r], 16, 64));
      rk[r] = min(rk[r], (unsigned)__shfl_xor((int)rk[r], 32, 64));
    }
    if (ksl == 0) {
#pragma unroll
      for (int r = 0; r < 4; ++r) {
        const int rowg = rbase + r * 16 + lr;
        wkey[(size_t)rowg * 2 + half] = rk[r];
        if (half == 0) wzz[rowg] = zz[r];
      }
    }
  }
}

// ---- K2: combine halves, gather z_q, partials ------------------------------
// 2048 blocks x 256 thr; 64 rows/block, 4 threads per row.
__global__ void __launch_bounds__(256) vq_out(
    const float* __restrict__ emb, float* __restrict__ out,
    char* __restrict__ ws) {
  const int tid = threadIdx.x;
  const int wave = tid >> 6, lane = tid & 63;
  const int row = tid >> 2, seg = tid & 3;
  const size_t rowg = (size_t)blockIdx.x * 64 + row;

  const unsigned* wkey = (const unsigned*)(ws + WS_KEY);
  const float* wzz = (const float*)(ws + WS_ZZ);

  const uint2 kk = ((const uint2*)wkey)[rowg];   // L1-broadcast across segs
  const unsigned k = min(kk.x, kk.y);
  const unsigned idx = k & 1023u;

  const f32x4* ep = (const f32x4*)(emb + (size_t)idx * 64 + seg * 16);
  f32x4* op = (f32x4*)(out + rowg * 64 + seg * 16);
#pragma unroll
  for (int c = 0; c < 4; ++c) op[c] = ep[c];

  float ls = 0.f; int s1 = 0, s2 = 0;
  if (seg == 0) {
    // d = ||z||^2 + (0.5 + ee - 2 z.e)_min - 0.5 ; low 10 bits were cleared
    ls = wzz[rowg] + __uint_as_float(k & 0xFFFFFC00u) - 0.5f;
    s1 = (int)idx;
    s2 = (int)(idx * idx);
    out[OUT_IDX + rowg] = (float)idx;
  }
#pragma unroll
  for (int off = 1; off < 64; off <<= 1) {
    ls += __shfl_xor(ls, off, 64);
    s1 += __shfl_xor(s1, off, 64);
    s2 += __shfl_xor(s2, off, 64);
  }
  __shared__ float sL[4];
  __shared__ int sA[4], sB[4];
  if (lane == 0) { sL[wave] = ls; sA[wave] = s1; sB[wave] = s2; }
  __syncthreads();
  if (tid == 0) {
    float L = 0; int a = 0, b = 0;
#pragma unroll
    for (int w = 0; w < 4; ++w) { L += sL[w]; a += sA[w]; b += sB[w]; }
    ((float*)(ws + WS_LOSS))[blockIdx.x] = L;
    ((int*)(ws + WS_S1))[blockIdx.x] = a;
    ((int*)(ws + WS_S2))[blockIdx.x] = b;
  }
}

// ---- K3: final scalar reduce over 2048 block partials ---------------------
__global__ void vq_final(float* __restrict__ out, const char* __restrict__ ws) {
  const int t = threadIdx.x;   // 256 threads
  const float* lp = (const float*)(ws + WS_LOSS);
  const int* p1 = (const int*)(ws + WS_S1);
  const int* p2 = (const int*)(ws + WS_S2);
  double L = 0; long long a = 0, b = 0;
#pragma unroll
  for (int kk = 0; kk < 8; ++kk) {
    const int i = t + 256 * kk;
    L += (double)lp[i];
    a += (long long)p1[i];
    b += (long long)p2[i];
  }
#pragma unroll
  for (int off = 1; off < 64; off <<= 1) {
    L += __shfl_xor(L, off, 64);
    a += __shfl_xor(a, off, 64);
    b += __shfl_xor(b, off, 64);
  }
  __shared__ double sLf[4];
  __shared__ long long sAf[4], sBf[4];
  const int wave = t >> 6, lane = t & 63;
  if (lane == 0) { sLf[wave] = L; sAf[wave] = a; sBf[wave] = b; }
  __syncthreads();
  if (t == 0) {
    double Lt = 0; long long at = 0, bt = 0;
#pragma unroll
    for (int w = 0; w < 4; ++w) { Lt += sLf[w]; at += sAf[w]; bt += sBf[w]; }
    // loss = (beta + 1) * mean((z_q - z)^2), beta = 0.25
    out[OUT_LOSS] = (float)(1.25 * Lt / 8388608.0);
    // var(idx, ddof=1) exact: (n*S2 - S1^2) / (n*(n-1))
    long long num = bt * 131072LL - at * at;
    out[OUT_VAR] = (float)((double)num / (131072.0 * 131071.0));
  }
}

extern "C" void kernel_launch(void* const* d_in, const int* in_sizes, int n_in,
                              void* d_out, int out_size, void* d_ws, size_t ws_size,
                              hipStream_t stream) {
  (void)in_sizes; (void)n_in; (void)out_size; (void)ws_size;
  const float* z = (const float*)d_in[0];
  const float* emb = (const float*)d_in[1];
  float* out = (float*)d_out;
  char* ws = (char*)d_ws;
  vq_prep<<<64, 64, 0, stream>>>(emb, ws);
  vq_dist<<<512, 256, 0, stream>>>(z, ws);
  vq_out<<<2048, 256, 0, stream>>>(emb, out, ws);
  vq_final<<<1, 256, 0, stream>>>(out, ws);
}

// Round 13
// 45.067 us; speedup vs baseline: 1.2051x; 1.2051x over previous
//
#include <hip/hip_runtime.h>
#include <stdint.h>

// VQ-VAE quantization: B=131072 rows of z (D=64) vs N_E=1024 codes.
// Outputs (flat f32): z_q [131072*64] | loss [1] | idx [131072] | var(idx,ddof=1) [1]
//
// R13: 32x32x16 MFMA (halves MFMA inst count), FULL codebook resident in LDS
// (144 KB, staged once, zero loop traffic/barriers), K extended to 80: the 5th
// MFMA's A-column carries ||e||^2 (B-side unit vector), so C-in is a constant
// 0.5 vector and t = 0.5 + ||e||^2 - 2 z.e exactly as rounds 1-12.
// key = (float_bits(t) & ~1023) | code ; unsigned min == argmin, tie->lowest n.
// 256 blocks x 512 thr = 1 block/CU; each wave: 64 rows x all 1024 codes.

typedef __attribute__((ext_vector_type(8))) __bf16 bf16x8;
typedef __attribute__((ext_vector_type(4))) float f32x4;
typedef __attribute__((ext_vector_type(16))) float f32x16;

#define OUT_LOSS 8388608
#define OUT_IDX  8388609
#define OUT_VAR  8519681

// workspace layout (bytes)
#define WS_LOSS  0          // float[256] per-block loss partials
#define WS_S1    4096       // int[256] sum(idx)
#define WS_S2    8192       // int[256] sum(idx^2)
#define WS_EFRAG 12288      // bf16x8[32 tiles * 4 ksteps * 64 lanes] = 128 KB
#define WS_A4    143360     // bf16x8[32 tiles * 32 lanes] ee-column = 16 KB

__device__ __forceinline__ void gld_lds16(const void* g, void* l) {
  __builtin_amdgcn_global_load_lds(
      (const __attribute__((address_space(1))) unsigned*)g,
      (__attribute__((address_space(3))) unsigned*)l, 16, 0, 0);
}

// ---- K0: prep codebook fragments (32x32x16 A-layout) -----------------------
// A-frag: lane l holds code row (t*32 + (l&31)), k = ks*16 + (l>>5)*8 + i.
// Values are -2*e. A4 (K-extension): lanes<32 hold elem0 = bf16(||e||^2).
__global__ void vq_prep(const float* __restrict__ emb, char* __restrict__ ws) {
  bf16x8* efrag = (bf16x8*)(ws + WS_EFRAG);
  bf16x8* a4 = (bf16x8*)(ws + WS_A4);
  const int t = blockIdx.x;    // tile 0..31 (32 codes each)
  const int l = threadIdx.x;   // 0..63
  const int n = t * 32 + (l & 31);
  const int kb = (l >> 5) * 8;
  const float* er = emb + n * 64;
#pragma unroll
  for (int ks = 0; ks < 4; ++ks) {
    bf16x8 h;
#pragma unroll
    for (int i = 0; i < 8; ++i) h[i] = (__bf16)(-2.0f * er[ks * 16 + kb + i]);
    efrag[(t * 4 + ks) * 64 + l] = h;
  }
  if (l < 32) {
    float s = 0.f;
#pragma unroll
    for (int d = 0; d < 64; ++d) s += er[d] * er[d];
    bf16x8 h;
#pragma unroll
    for (int i = 0; i < 8; ++i) h[i] = (__bf16)0.f;
    h[0] = (__bf16)s;            // rel err 0.4% of <=6e-5 : negligible
    a4[t * 32 + l] = h;
  }
}

// ---- K1: distances + argmin + fused epilogue -------------------------------
// 256 blocks x 512 thr (8 waves); wave w owns rows blockIdx*512 + w*64 .. +63.
__global__ void __launch_bounds__(512) vq_main(
    const float* __restrict__ z, const float* __restrict__ emb,
    float* __restrict__ out, char* __restrict__ ws) {
  __shared__ char sfrag[131072];   // full codebook A-frags, resident
  __shared__ char sa4[16384];      // ee K-extension column
  __shared__ float sL[8];
  __shared__ int sA[8], sB[8];

  const int tid = threadIdx.x;
  const int wave = tid >> 6, lane = tid & 63;
  const int l31 = lane & 31, lh = lane >> 5;
  const int rb = blockIdx.x * 512 + wave * 64;

  // one-shot staging: 128K frags (16 passes) + 16K A4 (2 passes)
#pragma unroll
  for (int i = 0; i < 16; ++i)
    gld_lds16(ws + WS_EFRAG + i * 8192 + wave * 1024 + lane * 16,
              sfrag + i * 8192 + wave * 1024);
#pragma unroll
  for (int i = 0; i < 2; ++i)
    gld_lds16(ws + WS_A4 + i * 8192 + wave * 1024 + lane * 16,
              sa4 + i * 8192 + wave * 1024);

  // z B-fragments: col = lane&31 -> z-row rb + rg*32 + (lane&31);
  // k = ks*16 + (lane>>5)*8 + i. Lane covers 32 of the row's 64 dims.
  bf16x8 zb[2][4];
  float zzp[2];
#pragma unroll
  for (int rg = 0; rg < 2; ++rg) {
    const float* zp = z + (size_t)(rb + rg * 32 + l31) * 64 + lh * 8;
    float s = 0.f;
#pragma unroll
    for (int ks = 0; ks < 4; ++ks) {
      f32x4 v0 = *(const f32x4*)(zp + ks * 16);
      f32x4 v1 = *(const f32x4*)(zp + ks * 16 + 4);
      bf16x8 h;
#pragma unroll
      for (int i = 0; i < 4; ++i) {
        h[i] = (__bf16)v0[i]; h[4 + i] = (__bf16)v1[i];
        s += v0[i] * v0[i] + v1[i] * v1[i];
      }
      zb[rg][ks] = h;
    }
    zzp[rg] = s;
  }
  // B4 unit vector: k=0 slot only (lanes<32, elem0)
  bf16x8 zb4;
#pragma unroll
  for (int i = 0; i < 8; ++i) zb4[i] = (__bf16)0.f;
  if (lh == 0) zb4[0] = (__bf16)1.0f;

  // constant C-in = 0.5
  f32x16 half16;
#pragma unroll
  for (int i = 0; i < 16; ++i) half16[i] = 0.5f;

  asm volatile("s_waitcnt vmcnt(0)" ::: "memory");
  __syncthreads();                  // staging visible; ONLY loop-wide barrier

  const bf16x8* fr = (const bf16x8*)sfrag;
  const bf16x8* a4 = (const bf16x8*)sa4;
  unsigned rk0 = 0xFFFFFFFFu, rk1 = 0xFFFFFFFFu;
  const unsigned vbase = 4u * (unsigned)lh;

#pragma unroll
  for (int t = 0; t < 32; ++t) {
    const bf16x8 A0 = fr[(t * 4 + 0) * 64 + lane];
    const bf16x8 A1 = fr[(t * 4 + 1) * 64 + lane];
    const bf16x8 A2 = fr[(t * 4 + 2) * 64 + lane];
    const bf16x8 A3 = fr[(t * 4 + 3) * 64 + lane];
    const bf16x8 A4v = a4[t * 32 + l31];      // lanes 32-63: broadcast dup
    __builtin_amdgcn_s_setprio(1);
    f32x16 c0 = __builtin_amdgcn_mfma_f32_32x32x16_bf16(A0, zb[0][0], half16, 0, 0, 0);
    c0 = __builtin_amdgcn_mfma_f32_32x32x16_bf16(A1, zb[0][1], c0, 0, 0, 0);
    c0 = __builtin_amdgcn_mfma_f32_32x32x16_bf16(A2, zb[0][2], c0, 0, 0, 0);
    c0 = __builtin_amdgcn_mfma_f32_32x32x16_bf16(A3, zb[0][3], c0, 0, 0, 0);
    c0 = __builtin_amdgcn_mfma_f32_32x32x16_bf16(A4v, zb4, c0, 0, 0, 0);
    f32x16 c1 = __builtin_amdgcn_mfma_f32_32x32x16_bf16(A0, zb[1][0], half16, 0, 0, 0);
    c1 = __builtin_amdgcn_mfma_f32_32x32x16_bf16(A1, zb[1][1], c1, 0, 0, 0);
    c1 = __builtin_amdgcn_mfma_f32_32x32x16_bf16(A2, zb[1][2], c1, 0, 0, 0);
    c1 = __builtin_amdgcn_mfma_f32_32x32x16_bf16(A3, zb[1][3], c1, 0, 0, 0);
    c1 = __builtin_amdgcn_mfma_f32_32x32x16_bf16(A4v, zb4, c1, 0, 0, 0);
    __builtin_amdgcn_s_setprio(0);
    // keys: C row (code-in-tile) = (reg&3) + 8*(reg>>2) + 4*(lane>>5)
    unsigned q[16];
#pragma unroll
    for (int r = 0; r < 16; ++r)
      q[r] = (__float_as_uint(c0[r]) & 0xFFFFFC00u) | (unsigned)((r & 3) + 8 * (r >> 2));
#pragma unroll
    for (int s = 8; s > 0; s >>= 1)
#pragma unroll
      for (int i = 0; i < 8; ++i) if (i < s) q[i] = min(q[i], q[i + s]);
    rk0 = min(rk0, q[0] + vbase + (unsigned)(t * 32));
#pragma unroll
    for (int r = 0; r < 16; ++r)
      q[r] = (__float_as_uint(c1[r]) & 0xFFFFFC00u) | (unsigned)((r & 3) + 8 * (r >> 2));
#pragma unroll
    for (int s = 8; s > 0; s >>= 1)
#pragma unroll
      for (int i = 0; i < 8; ++i) if (i < s) q[i] = min(q[i], q[i + s]);
    rk1 = min(rk1, q[0] + vbase + (unsigned)(t * 32));
  }

  // combine the two code-offset halves (lane <-> lane^32); complete zz
  rk0 = min(rk0, (unsigned)__shfl_xor((int)rk0, 32, 64));
  rk1 = min(rk1, (unsigned)__shfl_xor((int)rk1, 32, 64));
  float zz0 = zzp[0] + __shfl_xor(zzp[0], 32, 64);
  float zz1 = zzp[1] + __shfl_xor(zzp[1], 32, 64);

  // epilogue: lane handles row rb + lane (lane<32 -> rg0, else rg1)
  const unsigned key = (lane < 32) ? rk0 : rk1;
  const float zzv = (lane < 32) ? zz0 : zz1;
  const unsigned idx = key & 1023u;
  const size_t rowg = (size_t)rb + lane;
  const f32x4* ep = (const f32x4*)(emb + (size_t)idx * 64);
  f32x4* op = (f32x4*)(out + rowg * 64);
#pragma unroll
  for (int c = 0; c < 16; ++c) op[c] = ep[c];
  out[OUT_IDX + rowg] = (float)idx;

  // per-lane partials (one row each): d = zz + (0.5 + ee - 2 z.e)_min - 0.5
  float ls = zzv + __uint_as_float(key & 0xFFFFFC00u) - 0.5f;
  int s1 = (int)idx;
  int s2 = (int)(idx * idx);
#pragma unroll
  for (int off = 1; off < 64; off <<= 1) {
    ls += __shfl_xor(ls, off, 64);
    s1 += __shfl_xor(s1, off, 64);
    s2 += __shfl_xor(s2, off, 64);
  }
  if (lane == 0) { sL[wave] = ls; sA[wave] = s1; sB[wave] = s2; }
  __syncthreads();
  if (tid == 0) {
    float L = 0; int a = 0, b = 0;
#pragma unroll
    for (int w = 0; w < 8; ++w) { L += sL[w]; a += sA[w]; b += sB[w]; }
    ((float*)(ws + WS_LOSS))[blockIdx.x] = L;
    ((int*)(ws + WS_S1))[blockIdx.x] = a;
    ((int*)(ws + WS_S2))[blockIdx.x] = b;
  }
}

// ---- K2: final scalar reduce over 256 block partials -----------------------
__global__ void vq_final(float* __restrict__ out, const char* __restrict__ ws) {
  const int t = threadIdx.x;   // 256 threads, 1 partial each
  const float* lp = (const float*)(ws + WS_LOSS);
  const int* p1 = (const int*)(ws + WS_S1);
  const int* p2 = (const int*)(ws + WS_S2);
  double L = (double)lp[t];
  long long a = (long long)p1[t];
  long long b = (long long)p2[t];
#pragma unroll
  for (int off = 1; off < 64; off <<= 1) {
    L += __shfl_xor(L, off, 64);
    a += __shfl_xor(a, off, 64);
    b += __shfl_xor(b, off, 64);
  }
  __shared__ double sLf[4];
  __shared__ long long sAf[4], sBf[4];
  const int wave = t >> 6, lane = t & 63;
  if (lane == 0) { sLf[wave] = L; sAf[wave] = a; sBf[wave] = b; }
  __syncthreads();
  if (t == 0) {
    double Lt = 0; long long at = 0, bt = 0;
#pragma unroll
    for (int w = 0; w < 4; ++w) { Lt += sLf[w]; at += sAf[w]; bt += sBf[w]; }
    // loss = (beta + 1) * mean((z_q - z)^2), beta = 0.25
    out[OUT_LOSS] = (float)(1.25 * Lt / 8388608.0);
    // var(idx, ddof=1) exact: (n*S2 - S1^2) / (n*(n-1))
    long long num = bt * 131072LL - at * at;
    out[OUT_VAR] = (float)((double)num / (131072.0 * 131071.0));
  }
}

extern "C" void kernel_launch(void* const* d_in, const int* in_sizes, int n_in,
                              void* d_out, int out_size, void* d_ws, size_t ws_size,
                              hipStream_t stream) {
  (void)in_sizes; (void)n_in; (void)out_size; (void)ws_size;
  const float* z = (const float*)d_in[0];
  const float* emb = (const float*)d_in[1];
  float* out = (float*)d_out;
  char* ws = (char*)d_ws;
  vq_prep<<<32, 64, 0, stream>>>(emb, ws);
  vq_main<<<256, 512, 0, stream>>>(z, emb, out, ws);
  vq_final<<<1, 256, 0, stream>>>(out, ws);
}